// Round 3
// baseline (1608.817 us; speedup 1.0000x reference)
//
#include <hip/hip_runtime.h>

#define N_P 50000
#define N_HE 5000
#define N_E 800000
#define D_IN 128
#define D_HID 256
#define N_HEADS 4
#define HEAD_DIM 64

// ---------------- zero-fill workspace (no hipMemsetAsync) ----------------
__global__ void k_zero(float* __restrict__ p, unsigned n) {
    unsigned i = blockIdx.x * blockDim.x + threadIdx.x;
    unsigned stride = gridDim.x * blockDim.x;
    for (; i < n; i += stride) p[i] = 0.f;
}

// ---------------- Stage 1: he_feat[hid] += feat[pid] * w ----------------
__global__ void k_scatter_he(
    const float* __restrict__ feat, const float* __restrict__ edge_w,
    const int* __restrict__ edge_pid, const int* __restrict__ edge_hid,
    float* __restrict__ he_feat) {
    unsigned i = blockIdx.x * blockDim.x + threadIdx.x;
    unsigned stride = gridDim.x * blockDim.x;
    const unsigned total = (unsigned)N_E * D_IN;
    for (; i < total; i += stride) {
        unsigned e = i >> 7;
        unsigned d = i & 127u;
        float w = edge_w[e];
        float v = feat[(unsigned)edge_pid[e] * D_IN + d] * w;
        atomicAdd(he_feat + (unsigned)edge_hid[e] * D_IN + d, v);
    }
}

// ---------------- Stage 2: attention; he_feat row scaled IN PLACE ----------------
__global__ void k_attn(
    float* __restrict__ he_feat,
    const float* __restrict__ Wh1, const float* __restrict__ bh1,
    const float* __restrict__ Wh2, const float* __restrict__ bh2,
    const float* __restrict__ Wfuse) {
    __shared__ float hef[D_IN];
    __shared__ float attnv[N_HEADS];
    __shared__ float heattn;
    int t = threadIdx.x;      // 256 threads = 4 waves; wave == head
    int head = t >> 6;
    int k = t & 63;
    for (int n = blockIdx.x; n < N_HE; n += gridDim.x) {
        if (t < D_IN) hef[t] = he_feat[n * D_IN + t];
        __syncthreads();
        float s = bh1[head * HEAD_DIM + k];
        for (int d = 0; d < D_IN; ++d)
            s += hef[d] * Wh1[(head * D_IN + d) * HEAD_DIM + k];
        s = fmaxf(s, 0.f);                          // relu
        float val = s * Wh2[head * HEAD_DIM + k];
        for (int off = 32; off; off >>= 1) val += __shfl_down(val, off);
        if (k == 0) {
            float x = val + bh2[head];
            attnv[head] = 1.f / (1.f + expf(-x));   // sigmoid
        }
        __syncthreads();
        if (t == 0) {
            float ha = 0.f;
            for (int h = 0; h < N_HEADS; ++h) ha += attnv[h] * Wfuse[h];
            heattn = ha;
        }
        __syncthreads();
        if (t < D_IN) he_feat[n * D_IN + t] = hef[t] * heattn;  // row fully staged above
        __syncthreads();
    }
}

// ---------------- Stage 3: cluster_feat[pid] += he_weighted[hid] * w ----------------
__global__ void k_scatter_clu(
    const float* __restrict__ he_weighted, const float* __restrict__ edge_w,
    const int* __restrict__ edge_pid, const int* __restrict__ edge_hid,
    float* __restrict__ cluster_feat) {
    unsigned i = blockIdx.x * blockDim.x + threadIdx.x;
    unsigned stride = gridDim.x * blockDim.x;
    const unsigned total = (unsigned)N_E * D_IN;
    for (; i < total; i += stride) {
        unsigned e = i >> 7;
        unsigned d = i & 127u;
        float w = edge_w[e];
        float v = he_weighted[(unsigned)edge_hid[e] * D_IN + d] * w;
        atomicAdd(cluster_feat + (unsigned)edge_pid[e] * D_IN + d, v);
    }
}

// ---------------- Stage 4: per-protein fused MLP ----------------
__global__ void k_final(
    const float* __restrict__ feat, const float* __restrict__ cluster_feat,
    const float* __restrict__ Wself, const float* __restrict__ bself,
    const float* __restrict__ Wclu, const float* __restrict__ bclu,
    const float* __restrict__ Wf1, const float* __restrict__ bf1,
    const float* __restrict__ Wf2, const float* __restrict__ bf2,
    const float* __restrict__ Wf3, const float* __restrict__ bf3,
    float* __restrict__ out) {
    __shared__ float featL[D_IN];
    __shared__ float catL[2 * D_IN];
    __shared__ float h1[D_HID];
    __shared__ float h2[D_HID / 2];
    __shared__ float lg[2];
    int t = threadIdx.x;

    for (int p = blockIdx.x; p < N_P; p += gridDim.x) {
        if (t < D_IN) featL[t] = feat[p * D_IN + t];
        __syncthreads();

        // self_f / clu_f -> cat  (threads 0-127: self, 128-255: clu)
        if (t < 128) {
            int j = t;
            float s = bself[j];
            for (int d = 0; d < 128; ++d) s += featL[d] * Wself[d * 128 + j];
            catL[j] = s;
        } else {
            int j = t - 128;
            float s = bclu[j];
            const float* cf = cluster_feat + p * D_IN;
            for (int d = 0; d < 128; ++d) s += cf[d] * Wclu[d * 128 + j];
            catL[128 + j] = s;
        }
        __syncthreads();

        // h1 = relu(cat @ Wf1 + bf1)
        {
            float s = bf1[t];
            for (int d = 0; d < 256; ++d) s += catL[d] * Wf1[d * 256 + t];
            h1[t] = fmaxf(s, 0.f);
        }
        __syncthreads();

        // h2 = relu(h1 @ Wf2 + bf2)
        if (t < 128) {
            float s = bf2[t];
            for (int d = 0; d < 256; ++d) s += h1[d] * Wf2[d * 128 + t];
            h2[t] = fmaxf(s, 0.f);
        }
        __syncthreads();

        // logits = h2 @ Wf3 + bf3 : wave0 -> logit0, wave1 -> logit1
        if (t < 128) {
            int w = t >> 6;
            int l = t & 63;
            float partial = h2[l] * Wf3[l * 2 + w] +
                            h2[l + 64] * Wf3[(l + 64) * 2 + w];
            for (int off = 32; off; off >>= 1) partial += __shfl_down(partial, off);
            if (l == 0) lg[w] = partial + bf3[w];
        }
        __syncthreads();

        if (t < 128) {
            float l0 = lg[0], l1 = lg[1];
            float m = fmaxf(l0, l1);
            float e0 = expf(l0 - m), e1 = expf(l1 - m);
            float inv = 1.f / (e0 + e1);
            float fused = catL[t] * (e0 * inv) + catL[128 + t] * (e1 * inv);
            float v = fused + featL[t];
            // diagnostic: pass NaN through instead of flushing it via fmaxf,
            // so a dtype/garbage failure is distinguishable from "didn't run"
            float r = fmaxf(v, 0.f);
            out[p * D_IN + t] = (v == v) ? r : v;
        }
        __syncthreads();   // protect shared reuse across grid-stride iterations
    }
}

extern "C" void kernel_launch(void* const* d_in, const int* in_sizes, int n_in,
                              void* d_out, int out_size, void* d_ws, size_t ws_size,
                              hipStream_t stream) {
    (void)in_sizes; (void)n_in; (void)out_size; (void)ws_size;
    const float* feat   = (const float*)d_in[0];
    const float* edge_w = (const float*)d_in[1];
    const float* Wself  = (const float*)d_in[2];
    const float* bself  = (const float*)d_in[3];
    const float* Wclu   = (const float*)d_in[4];
    const float* bclu   = (const float*)d_in[5];
    const float* Wh1    = (const float*)d_in[6];
    const float* bh1    = (const float*)d_in[7];
    const float* Wh2    = (const float*)d_in[8];
    const float* bh2    = (const float*)d_in[9];
    const float* Wfuse  = (const float*)d_in[10];
    const float* Wf1    = (const float*)d_in[11];
    const float* bf1_   = (const float*)d_in[12];
    const float* Wf2    = (const float*)d_in[13];
    const float* bf2_   = (const float*)d_in[14];
    const float* Wf3    = (const float*)d_in[15];
    const float* bf3_   = (const float*)d_in[16];
    const int* edge_pid = (const int*)d_in[17];
    const int* edge_hid = (const int*)d_in[18];
    float* out = (float*)d_out;

    float* he_feat      = (float*)d_ws;                         // N_HE*D_IN (weighted in place)
    float* cluster_feat = he_feat + (size_t)N_HE * D_IN;        // N_P*D_IN
    unsigned zero_elems = (unsigned)(N_HE * D_IN + N_P * D_IN); // 7,040,000 floats

    k_zero<<<2048, 256, 0, stream>>>((float*)d_ws, zero_elems);
    k_scatter_he<<<4096, 256, 0, stream>>>(feat, edge_w, edge_pid, edge_hid, he_feat);
    k_attn<<<2048, 256, 0, stream>>>(he_feat, Wh1, bh1, Wh2, bh2, Wfuse);
    k_scatter_clu<<<4096, 256, 0, stream>>>(he_feat, edge_w, edge_pid, edge_hid, cluster_feat);
    k_final<<<4096, 256, 0, stream>>>(feat, cluster_feat, Wself, bself, Wclu, bclu,
                                      Wf1, bf1_, Wf2, bf2_, Wf3, bf3_, out);
}